// Round 11
// baseline (379.269 us; speedup 1.0000x reference)
//
#include <hip/hip_runtime.h>
#include <math.h>

#define N_NODES 20000
#define E_EDGES 320000
#define F_DIM   960
#define S_DIM   256
#define QTAB    2048
#define ASTRIDE 264   // LDS A row stride in bf16 elems
#define CAP     64    // max deg per node (Poisson(16): P(deg>=64) ~ 2e-18)
#define CPAD    66    // LDS per-node array stride (floats), conflict-free

typedef __attribute__((ext_vector_type(8))) short short8;
typedef __attribute__((ext_vector_type(4))) float f32x4;

__device__ __forceinline__ float siluf(float x) {
    return x / (1.0f + __expf(-x));
}

__device__ __forceinline__ unsigned short bf16rn(float x) {
    unsigned u = __float_as_uint(x);
    return (unsigned short)((u + 0x7FFFu + ((u >> 16) & 1u)) >> 16);
}

__device__ __forceinline__ void bf16x8_to_f32(short8 v8, float* o) {
    union { short8 s; uint4 u; } cv; cv.s = v8;
    o[0] = __uint_as_float(cv.u.x << 16);
    o[1] = __uint_as_float(cv.u.x & 0xffff0000u);
    o[2] = __uint_as_float(cv.u.y << 16);
    o[3] = __uint_as_float(cv.u.y & 0xffff0000u);
    o[4] = __uint_as_float(cv.u.z << 16);
    o[5] = __uint_as_float(cv.u.z & 0xffff0000u);
    o[6] = __uint_as_float(cv.u.w << 16);
    o[7] = __uint_as_float(cv.u.w & 0xffff0000u);
}

// ---------------------------------------------------------------------------
// A: fold weights (fp32 Bcat 256x1024, We 32x256, c0 256) + zero cnt.
// ---------------------------------------------------------------------------
__global__ void prep_kernel(const float* __restrict__ W_sc, const float* __restrict__ W_ed,
                            const float* __restrict__ W_b1, const float* __restrict__ b_sc,
                            const float* __restrict__ b_ed, const float* __restrict__ b_b1,
                            const float* __restrict__ W_ai1, const float* __restrict__ W_ci1,
                            float* __restrict__ Bcat, float* __restrict__ We, float* __restrict__ c0,
                            int* __restrict__ cnt)
{
    int idx = blockIdx.x * 256 + threadIdx.x;
    if (idx < N_NODES) cnt[idx] = 0;
    if (idx < 256 * 1024) {
        int k = idx >> 10, j = idx & 1023;
        float s = 0.0f;
        if (j < 256) {
            for (int m = 0; m < 256; ++m) s += W_sc[k * 256 + m] * W_b1[m * 256 + j];
        } else if (j < 512) {
            int jj = j - 256;
            for (int m = 0; m < 256; ++m) s += W_sc[k * 256 + m] * W_b1[(256 + m) * 256 + jj];
        } else if (j < 768) {
            s = W_ai1[k * 256 + (j - 512)];
        } else {
            s = W_ci1[k * 256 + (j - 768)];
        }
        Bcat[idx] = s;
    } else if (idx < 256 * 1024 + 32 * 256) {
        int t = idx - 256 * 1024;
        int p = t >> 8, j = t & 255;
        float s = 0.0f;
        for (int m = 0; m < 256; ++m) s += W_ed[p * 256 + m] * W_b1[(512 + m) * 256 + j];
        We[t] = s;
    } else if (idx < 256 * 1024 + 32 * 256 + 256) {
        int j = idx - 256 * 1024 - 32 * 256;
        float s = b_b1[j];
        for (int m = 0; m < 256; ++m) {
            s += b_sc[m] * (W_b1[m * 256 + j] + W_b1[(256 + m) * 256 + j]);
            s += b_ed[m] * W_b1[(512 + m) * 256 + j];
        }
        c0[j] = s;
    }
}

// ---------------------------------------------------------------------------
// B: fused rank-histogram + Bpack + TabV(f32) + scal->bf16 pack.
// Blocks: [0,1250) rank, [1250,1378) pack, [1378,3426) table, [3426,8426) scalp.
// ---------------------------------------------------------------------------
__global__ void aux_kernel(const int* __restrict__ ei, int* __restrict__ cnt, int* __restrict__ rank,
                           const float* __restrict__ Bcat, unsigned short* __restrict__ Bpack,
                           const float* __restrict__ We, float* __restrict__ TabV,
                           const float* __restrict__ nf, unsigned short* __restrict__ scalp)
{
    int b = blockIdx.x;
    if (b < 1250) {
        int i = b * 256 + threadIdx.x;          // 320000 exact
        rank[i] = atomicAdd(&cnt[ei[E_EDGES + i]], 1);
    } else if (b < 1378) {
        int idx = (b - 1250) * 256 + threadIdx.x;  // 32768 exact
        int kq = idx & 3, j = (idx >> 2) & 1023, t = idx >> 12;
        #pragma unroll
        for (int jj = 0; jj < 8; ++jj)
            Bpack[idx * 8 + jj] = bf16rn(Bcat[(t * 32 + kq * 8 + jj) * 1024 + j]);
    } else if (b < 3426) {
        int idx = (b - 1378) * 256 + threadIdx.x;  // 524288 exact
        int q = idx >> 8, j = idx & 255;
        float nrm = 5.0f * (float)q / (float)(QTAB - 1);
        const float start = 0.006737946999085467f;  // exp(-5)
        const float mustep = (1.0f - start) / 31.0f;
        const float bx = (2.0f / 32.0f) * (1.0f - start);
        const float beta = 1.0f / (bx * bx);
        const float PI_F = 3.14159265358979323846f;
        float cc = (nrm < 5.0f) ? 0.5f * (cosf(PI_F * nrm * 0.2f) + 1.0f) : 0.0f;
        float t = expf(-nrm);
        float s = 0.0f;
        for (int k = 0; k < 32; ++k) {
            float dm = t - (start + (float)k * mustep);
            s += expf(-beta * dm * dm) * We[k * 256 + j];
        }
        TabV[idx] = cc * s;
    } else {
        int idx = (b - 3426) * 256 + threadIdx.x;  // 1.28M exact (x4 elems)
        int base = idx * 4;
        int n = base >> 8, k = base & 255;
        float4 a4 = *(const float4*)&nf[(size_t)n * F_DIM + k];
        ushort4 b4;
        b4.x = bf16rn(a4.x); b4.y = bf16rn(a4.y);
        b4.z = bf16rn(a4.z); b4.w = bf16rn(a4.w);
        *(ushort4*)&scalp[n * 256 + k] = b4;
    }
}

// C: one block, 1024 threads, 20 nodes/thread exclusive scan of cnt.
__global__ __launch_bounds__(1024) void scan_kernel(const int* __restrict__ cnt,
                                                    int* __restrict__ start)
{
    __shared__ int ps[1024];
    const int t = threadIdx.x;
    const int base = t * 20;
    int loc[20];
    int s = 0;
    #pragma unroll
    for (int i = 0; i < 20; ++i) {
        int n = (base + i < N_NODES) ? cnt[base + i] : 0;
        loc[i] = s; s += n;
    }
    ps[t] = s;
    __syncthreads();
    for (int off = 1; off < 1024; off <<= 1) {
        int v = (t >= off) ? ps[t - off] : 0;
        __syncthreads();
        ps[t] += v;
        __syncthreads();
    }
    int offset = ps[t] - s;   // exclusive
    #pragma unroll
    for (int i = 0; i < 20; ++i)
        if (base + i < N_NODES) start[base + i] = offset + loc[i];
}

// ---------------------------------------------------------------------------
// D: fused (all independent, all need scan/aux done):
//   [0,625)      node GEMM via bf16 MFMA — A staged ONCE, wave w = col-group w
//   [625,1875)   atomic-free CSR scatter
//   [1875,3923)  TabD build (lerp delta rows)
// ---------------------------------------------------------------------------
__global__ __launch_bounds__(256) void mid_kernel(
    // mfma args
    const unsigned short* __restrict__ scalp, const unsigned short* __restrict__ Bpack,
    const float* __restrict__ c0,
    const float* __restrict__ b_ai1, const float* __restrict__ W_ai2, const float* __restrict__ b_ai2,
    const float* __restrict__ b_ci1, const float* __restrict__ W_ci2, const float* __restrict__ b_ci2,
    float* __restrict__ u, unsigned short* __restrict__ v,
    float* __restrict__ bsumseed, float* __restrict__ out_ai,
    // scatter args
    const int* __restrict__ ei, const int* __restrict__ start, const int* __restrict__ rank,
    int* __restrict__ srcS,
    // TabD args
    const float* __restrict__ TabV, float* __restrict__ TabD)
{
    __shared__ unsigned short A[32 * ASTRIDE];
    const int tid = threadIdx.x;

    if (blockIdx.x >= 625) {
        if (blockIdx.x < 1875) {
            int i = (blockIdx.x - 625) * 256 + tid;   // 320000 exact
            srcS[start[ei[E_EDGES + i]] + rank[i]] = ei[i];
        } else {
            int idx = (blockIdx.x - 1875) * 256 + tid;  // 524288 exact
            TabD[idx] = (idx < (QTAB - 1) * 256) ? TabV[idx + 256] - TabV[idx] : 0.0f;
        }
        return;
    }

    const int w = tid >> 6, lane = tid & 63;
    const int m0 = blockIdx.x * 32;
    const int col16 = lane & 15, quad = lane >> 4;

    #pragma unroll
    for (int it = 0; it < 4; ++it) {
        int idx = (it * 256 + tid) * 8;          // bf16 elem 0..8191
        int r = idx >> 8, c = idx & 255;
        *(uint4*)&A[r * ASTRIDE + c] = *(const uint4*)&scalp[(m0 + r) * 256 + c];
    }
    __syncthreads();

    f32x4 acc[2][16];
    #pragma unroll
    for (int mt = 0; mt < 2; ++mt)
        #pragma unroll
        for (int nt = 0; nt < 16; ++nt)
            acc[mt][nt] = (f32x4){0.0f, 0.0f, 0.0f, 0.0f};

    const int colbase = w * 256;

    for (int t = 0; t < 8; ++t) {
        short8 af[2];
        #pragma unroll
        for (int mt = 0; mt < 2; ++mt)
            af[mt] = *(const short8*)&A[(mt * 16 + col16) * ASTRIDE + t * 32 + quad * 8];
        #pragma unroll
        for (int nt = 0; nt < 16; ++nt) {
            short8 bf = *(const short8*)&Bpack[(((t * 1024 + colbase + nt * 16 + col16) * 4) + quad) * 8];
            acc[0][nt] = __builtin_amdgcn_mfma_f32_16x16x32_bf16(af[0], bf, acc[0][nt], 0, 0, 0);
            acc[1][nt] = __builtin_amdgcn_mfma_f32_16x16x32_bf16(af[1], bf, acc[1][nt], 0, 0, 0);
        }
    }

    // Epilogues. C/D: col = lane&15, row = quad*4 + reg. Wave w owns group w.
    if (w == 0) {
        #pragma unroll
        for (int nt = 0; nt < 16; ++nt) {
            int jl = nt * 16 + col16;
            float c0v = c0[jl];
            #pragma unroll
            for (int mt = 0; mt < 2; ++mt)
                #pragma unroll
                for (int reg = 0; reg < 4; ++reg)
                    u[(size_t)(m0 + mt * 16 + quad * 4 + reg) * 256 + jl] = acc[mt][nt][reg] + c0v;
        }
    } else if (w == 1) {
        #pragma unroll
        for (int nt = 0; nt < 16; ++nt) {
            int jl = nt * 16 + col16;
            #pragma unroll
            for (int mt = 0; mt < 2; ++mt)
                #pragma unroll
                for (int reg = 0; reg < 4; ++reg)
                    v[(size_t)(m0 + mt * 16 + quad * 4 + reg) * 256 + jl] = bf16rn(acc[mt][nt][reg]);
        }
    } else {
        const float* b1 = (w == 2) ? b_ai1 : b_ci1;
        const float* w2 = (w == 2) ? W_ai2 : W_ci2;
        float s[2][4] = {{0, 0, 0, 0}, {0, 0, 0, 0}};
        #pragma unroll
        for (int nt = 0; nt < 16; ++nt) {
            int jl = nt * 16 + col16;
            float bb = b1[jl], ww = w2[jl];
            #pragma unroll
            for (int mt = 0; mt < 2; ++mt)
                #pragma unroll
                for (int reg = 0; reg < 4; ++reg)
                    s[mt][reg] += siluf(acc[mt][nt][reg] + bb) * ww;
        }
        #pragma unroll
        for (int off = 1; off < 16; off <<= 1) {
            #pragma unroll
            for (int mt = 0; mt < 2; ++mt)
                #pragma unroll
                for (int reg = 0; reg < 4; ++reg)
                    s[mt][reg] += __shfl_xor(s[mt][reg], off);
        }
        if (col16 == 0) {
            #pragma unroll
            for (int mt = 0; mt < 2; ++mt)
                #pragma unroll
                for (int reg = 0; reg < 4; ++reg) {
                    int row = m0 + mt * 16 + quad * 4 + reg;
                    if (w == 2) out_ai[row] = expf(s[mt][reg] + b_ai2[0]);
                    else        bsumseed[row] = expf(s[mt][reg] + b_ci2[0]) + 1e-7f;  // ci + eps
                }
        }
    }
}

// ---------------------------------------------------------------------------
// F: fused per-node edge MLP + softmax + outer-product. 16 lanes/node,
// 4 nodes/wave. u fp32, Tab as (value,delta) fp32 -> zero unpacks in the
// channel loop. Next-edge pos/u prefetched.
// ---------------------------------------------------------------------------
__global__ __launch_bounds__(256) void edge_node_kernel(
    const int* __restrict__ start, const int* __restrict__ cnt, const int* __restrict__ srcS,
    const float* __restrict__ pos,
    const float* __restrict__ u, const unsigned short* __restrict__ v,
    const float* __restrict__ TabV, const float* __restrict__ TabD,
    const float* __restrict__ W_b2, const float* __restrict__ b_b2,
    const float* __restrict__ bsumseed, const float* __restrict__ out_ai,
    float* __restrict__ out_sigma, float* __restrict__ out_sg)
{
    __shared__ float sb[16][CPAD];
    __shared__ float srx[16][CPAD];
    __shared__ float sry[16][CPAD];
    __shared__ float srz[16][CPAD];

    const int grp = threadIdx.x >> 4;   // node-in-block 0..15
    const int l   = threadIdx.x & 15;
    const int g   = blockIdx.x * 16 + grp;   // grid exact: 1250*16 = 20000
    const int st  = start[g];
    const int deg = min(cnt[g], CAP);

    float vch[16];
    bf16x8_to_f32(*(const short8*)&v[(size_t)g * 256 + l * 16], vch);
    bf16x8_to_f32(*(const short8*)&v[(size_t)g * 256 + l * 16 + 8], vch + 8);
    float w2c[16];
    #pragma unroll
    for (int c = 0; c < 16; c += 4)
        *(float4*)&w2c[c] = *(const float4*)&W_b2[l * 16 + c];
    const float bb2 = b_b2[0];
    const float gx = pos[3 * g + 0], gy = pos[3 * g + 1], gz = pos[3 * g + 2];
    const float xscale = (float)(QTAB - 1) * 0.2f;

    int s_cur = (deg > 0) ? srcS[st] : 0;
    float pxc = pos[3 * s_cur + 0], pyc = pos[3 * s_cur + 1], pzc = pos[3 * s_cur + 2];
    float4 uc[4];
    #pragma unroll
    for (int cq = 0; cq < 4; ++cq)
        uc[cq] = *(const float4*)&u[(size_t)s_cur * 256 + l * 16 + cq * 4];

    for (int i = 0; i < deg; ++i) {
        // Prefetch next edge (independent loads before the dependent chain).
        int s_nxt = (i + 1 < deg) ? srcS[st + i + 1] : s_cur;
        float pxn = pos[3 * s_nxt + 0], pyn = pos[3 * s_nxt + 1], pzn = pos[3 * s_nxt + 2];
        float4 un[4];
        #pragma unroll
        for (int cq = 0; cq < 4; ++cq)
            un[cq] = *(const float4*)&u[(size_t)s_nxt * 256 + l * 16 + cq * 4];

        float px = gx - pxc, py = gy - pyc, pz = gz - pzc;
        float nrm = sqrtf(px * px + py * py + pz * pz);
        float inv = 1.0f / (nrm + 1e-8f);
        float rx = px * inv, ry = py * inv, rz = pz * inv;

        float x = nrm * xscale;
        int qi = (int)x;
        float f = x - (float)qi;
        if (qi >= QTAB - 1) { qi = QTAB - 2; f = 1.0f; }

        float acc = 0.0f;
        #pragma unroll
        for (int cq = 0; cq < 4; ++cq) {
            float4 tv = *(const float4*)&TabV[(size_t)qi * 256 + l * 16 + cq * 4];
            float4 td = *(const float4*)&TabD[(size_t)qi * 256 + l * 16 + cq * 4];
            float4 uu = uc[cq];
            float h0 = uu.x + vch[cq * 4 + 0] + tv.x + f * td.x;
            float h1 = uu.y + vch[cq * 4 + 1] + tv.y + f * td.y;
            float h2 = uu.z + vch[cq * 4 + 2] + tv.z + f * td.z;
            float h3 = uu.w + vch[cq * 4 + 3] + tv.w + f * td.w;
            acc += w2c[cq * 4 + 0] * h0 * __builtin_amdgcn_rcpf(1.0f + __expf(-h0));
            acc += w2c[cq * 4 + 1] * h1 * __builtin_amdgcn_rcpf(1.0f + __expf(-h1));
            acc += w2c[cq * 4 + 2] * h2 * __builtin_amdgcn_rcpf(1.0f + __expf(-h2));
            acc += w2c[cq * 4 + 3] * h3 * __builtin_amdgcn_rcpf(1.0f + __expf(-h3));
        }
        #pragma unroll
        for (int off = 1; off < 16; off <<= 1) acc += __shfl_xor(acc, off);

        if (l == 0) {
            sb[grp][i] = acc + bb2;
            srx[grp][i] = rx; sry[grp][i] = ry; srz[grp][i] = rz;
        }
        s_cur = s_nxt; pxc = pxn; pyc = pyn; pzc = pzn;
        uc[0] = un[0]; uc[1] = un[1]; uc[2] = un[2]; uc[3] = un[3];
    }

    // Softmax (exact reference semantics) + outer-product accumulation.
    float m = -1e30f;
    for (int i = l; i < deg; i += 16) m = fmaxf(m, sb[grp][i]);
    #pragma unroll
    for (int off = 1; off < 16; off <<= 1) m = fmaxf(m, __shfl_xor(m, off));

    float ssum = 0.0f;
    for (int i = l; i < deg; i += 16) ssum += __expf(sb[grp][i] - m);
    #pragma unroll
    for (int off = 1; off < 16; off <<= 1) ssum += __shfl_xor(ssum, off);

    float invt = 1.0f / (ssum + bsumseed[g]);   // seed = ci + 1e-7

    float a0 = 0, a1 = 0, a2 = 0, a3 = 0, a4 = 0, a5 = 0, a6 = 0;
    for (int i = l; i < deg; i += 16) {
        float gm = __expf(sb[grp][i] - m) * invt;
        float rx = srx[grp][i], ry = sry[grp][i], rz = srz[grp][i];
        a0 += gm * rx * rx; a1 += gm * ry * ry; a2 += gm * rz * rz;
        a3 += gm * rx * ry; a4 += gm * rx * rz; a5 += gm * ry * rz;
        a6 += gm;
    }
    #pragma unroll
    for (int off = 1; off < 16; off <<= 1) {
        a0 += __shfl_xor(a0, off); a1 += __shfl_xor(a1, off);
        a2 += __shfl_xor(a2, off); a3 += __shfl_xor(a3, off);
        a4 += __shfl_xor(a4, off); a5 += __shfl_xor(a5, off);
        a6 += __shfl_xor(a6, off);
    }

    if (l == 0) {
        float ai = out_ai[g];
        float* sg = &out_sigma[g * 9];
        float d0 = ai + 1e-6f;
        sg[0] = d0 - ai * a0;
        sg[1] = -ai * a3;
        sg[2] = -ai * a4;
        sg[3] = -ai * a3;
        sg[4] = d0 - ai * a1;
        sg[5] = -ai * a5;
        sg[6] = -ai * a4;
        sg[7] = -ai * a5;
        sg[8] = d0 - ai * a2;
        out_sg[g] = a6;
    }
}

extern "C" void kernel_launch(void* const* d_in, const int* in_sizes, int n_in,
                              void* d_out, int out_size, void* d_ws, size_t ws_size,
                              hipStream_t stream)
{
    const float* nf    = (const float*)d_in[0];
    const float* pos   = (const float*)d_in[1];
    const int*   ei    = (const int*)  d_in[2];
    const float* W_ai1 = (const float*)d_in[3];
    const float* b_ai1 = (const float*)d_in[4];
    const float* W_ai2 = (const float*)d_in[5];
    const float* b_ai2 = (const float*)d_in[6];
    const float* W_ci1 = (const float*)d_in[7];
    const float* b_ci1 = (const float*)d_in[8];
    const float* W_ci2 = (const float*)d_in[9];
    const float* b_ci2 = (const float*)d_in[10];
    const float* W_sc  = (const float*)d_in[11];
    const float* b_sc  = (const float*)d_in[12];
    const float* W_ed  = (const float*)d_in[13];
    const float* b_ed  = (const float*)d_in[14];
    const float* W_b1  = (const float*)d_in[15];
    const float* b_b1  = (const float*)d_in[16];
    const float* W_b2  = (const float*)d_in[17];
    const float* b_b2  = (const float*)d_in[18];

    // Byte-based bump allocator (256-B aligned).
    char* pb = (char*)d_ws;
    auto alloc = [&](size_t bytes) -> void* {
        void* r = (void*)pb;
        pb += (bytes + 255) & ~(size_t)255;
        return r;
    };
    float*          Bcat    = (float*)         alloc(262144 * 4);
    float*          We      = (float*)         alloc(8192 * 4);
    float*          c0      = (float*)         alloc(256 * 4);
    float*          TabV    = (float*)         alloc((size_t)QTAB * 256 * 4);
    float*          TabD    = (float*)         alloc((size_t)QTAB * 256 * 4);
    unsigned short* Bpack   = (unsigned short*)alloc((size_t)256 * 1024 * 2);
    unsigned short* scalp   = (unsigned short*)alloc((size_t)N_NODES * 256 * 2);
    float*          u       = (float*)         alloc((size_t)N_NODES * 256 * 4);
    unsigned short* v       = (unsigned short*)alloc((size_t)N_NODES * 256 * 2);
    float*          bsumseed= (float*)         alloc((size_t)N_NODES * 4);
    int*            cnt     = (int*)           alloc((size_t)N_NODES * 4);
    int*            startA  = (int*)           alloc((size_t)N_NODES * 4);
    int*            rank    = (int*)           alloc((size_t)E_EDGES * 4);
    int*            srcS    = (int*)           alloc((size_t)E_EDGES * 4);

    float* out       = (float*)d_out;
    float* out_sigma = out;                  // N*9
    float* out_ai    = out + N_NODES * 9;    // N
    float* out_sg    = out + N_NODES * 10;   // N

    prep_kernel<<<1058, 256, 0, stream>>>(W_sc, W_ed, W_b1, b_sc, b_ed, b_b1, W_ai1, W_ci1,
                                          Bcat, We, c0, cnt);
    aux_kernel<<<8426, 256, 0, stream>>>(ei, cnt, rank, Bcat, Bpack, We, TabV, nf, scalp);
    scan_kernel<<<1, 1024, 0, stream>>>(cnt, startA);
    mid_kernel<<<3923, 256, 0, stream>>>(scalp, Bpack, c0, b_ai1, W_ai2, b_ai2,
                                         b_ci1, W_ci2, b_ci2, u, v, bsumseed, out_ai,
                                         ei, startA, rank, srcS, TabV, TabD);
    edge_node_kernel<<<1250, 256, 0, stream>>>(startA, cnt, srcS, pos, u, v, TabV, TabD,
                                               W_b2, b_b2, bsumseed, out_ai, out_sigma, out_sg);
}